// Round 2
// baseline (408.782 us; speedup 1.0000x reference)
//
#include <hip/hip_runtime.h>
#include <stdint.h>

#define NSUP 1024
#define NQRY 32768
#define DIM  64
#define NCLS 64

typedef float  f32x4  __attribute__((ext_vector_type(4)));
typedef short  s16x8  __attribute__((ext_vector_type(8)));
typedef __bf16 bf16x8 __attribute__((ext_vector_type(8)));

static __device__ __forceinline__ unsigned short f2bf(float f) {
  unsigned u = __float_as_uint(f);
  u += 0x7FFFu + ((u >> 16) & 1u);           // round-to-nearest-even
  return (unsigned short)(u >> 16);
}

// ---------------- Kernel 1: normalize queries -> bf16 ----------------
__global__ __launch_bounds__(256) void prep_queries(const float* __restrict__ Xq,
                                                    unsigned short* __restrict__ Ybf) {
  int tid  = threadIdx.x;
  int lane = tid & 63;
  int wave = tid >> 6;
  int row  = blockIdx.x * 16 + wave * 4 + (lane >> 4);
  int cb   = (lane & 15) * 4;
  float4 v = *(const float4*)(Xq + row * 64 + cb);
  float ss = v.x * v.x + v.y * v.y + v.z * v.z + v.w * v.w;
  ss += __shfl_xor(ss, 1);
  ss += __shfl_xor(ss, 2);
  ss += __shfl_xor(ss, 4);
  ss += __shfl_xor(ss, 8);
  float inv = 1.0f / fmaxf(sqrtf(ss), 1e-12f);
  unsigned short a = f2bf(v.x * inv), b = f2bf(v.y * inv);
  unsigned short c = f2bf(v.z * inv), d = f2bf(v.w * inv);
  uint2 o;
  o.x = (unsigned)a | ((unsigned)b << 16);
  o.y = (unsigned)c | ((unsigned)d << 16);
  *(uint2*)(Ybf + row * 64 + cb) = o;
}

// ---------------- Kernel 2: fit (one block per class) ----------------
// sigma build -> Gauss-Jordan inverse -> A = 0.7*inv+0.3*I -> Cholesky A=LL^T
// outputs: LtG bf16 [j][e][d] = L^T (upper-tri), Bg f32 [j][e] = (L^T mu)[e]
__global__ __launch_bounds__(256) void fit_classes(
    const float* __restrict__ Xs, const int* __restrict__ ys,
    const float* __restrict__ mg, const float* __restrict__ Sg,
    const float* __restrict__ nug, const float* __restrict__ kapg,
    unsigned short* __restrict__ LtG, float* __restrict__ Bg) {
  __shared__ int   yls[NSUP];
  __shared__ float Sls[64 * 66];
  __shared__ float xsch[16][64];
  __shared__ float mls[64];
  __shared__ float muls[64];
  __shared__ float Als[64 * 66];
  __shared__ float fcol[64];
  __shared__ float prow[64];
  __shared__ int   lst[NSUP];
  __shared__ int   cnts[2];

  int tid = threadIdx.x;
  int j   = blockIdx.x;

  for (int i = tid; i < NSUP; i += 256) yls[i] = ys[i];
  for (int i = tid; i < 4096; i += 256) Sls[(i >> 6) * 66 + (i & 63)] = Sg[i];
  if (tid < 64) mls[tid] = mg[tid];
  __syncthreads();

  // wave 0: match list + counts (Nj and reference's N0 = count of class 0)
  if (tid < 64) {
    int lane = tid;
    int cnt = 0, n0 = 0;
    for (int b = 0; b < NSUP; b += 64) {
      int yv = yls[b + lane];
      unsigned long long mj = __ballot(yv == j);
      unsigned long long m0 = __ballot(yv == 0);
      if (lane == 0) {
        n0 += (int)__popcll(m0);
        while (mj) { int bit = __builtin_ctzll(mj); lst[cnt++] = b + bit; mj &= mj - 1; }
      }
    }
    if (lane == 0) { cnts[0] = cnt; cnts[1] = n0; }
  }
  __syncthreads();
  int cnt = cnts[0], n0 = cnts[1];

  // accumulate Ssum (thread: row r_=tid&63, 16-col chunk) and sum_x
  int r_   = tid & 63;
  int cblk = tid >> 6;
  int c0   = cblk * 16;
  float accS[16];
#pragma unroll
  for (int i = 0; i < 16; ++i) accS[i] = 0.f;
  float sumx = 0.f;

  for (int s0 = 0; s0 < cnt; s0 += 16) {
    int nch = min(16, cnt - s0);
    if (tid < 64) {
      for (int s = 0; s < nch; ++s) {
        int n = lst[s0 + s];
        float v = Xs[n * 64 + tid];
        float ss = v * v;
        ss += __shfl_xor(ss, 1);  ss += __shfl_xor(ss, 2);
        ss += __shfl_xor(ss, 4);  ss += __shfl_xor(ss, 8);
        ss += __shfl_xor(ss, 16); ss += __shfl_xor(ss, 32);
        float inv = 1.0f / fmaxf(sqrtf(ss), 1e-12f);
        xsch[s][tid] = v * inv;
      }
    }
    __syncthreads();
    for (int s = 0; s < nch; ++s) {
      float a = xsch[s][r_];
      if (cblk == 0) sumx += a;
#pragma unroll
      for (int i = 0; i < 16; ++i) accS[i] += a * xsch[s][c0 + i];
    }
    __syncthreads();
  }

  float kap = kapg[0];
  float nuv = nug[0];
  if (tid < 64) {
    float Njf = (float)cnt, N0f = (float)n0;
    float mean = sumx / Njf;
    float head = kap / (kap + N0f) * mls[tid] + N0f / (kap + N0f);
    muls[tid] = head * mean;
  }
  __syncthreads();

  // sigma = left * (middle + Ssum + kappa*m m^T - (kappa+Nj) mu mu^T)
  {
    float Njf  = (float)cnt;
    float left = 1.0f / (nuv + Njf + (float)DIM + 2.0f);
    float kn   = kap + Njf;
    float mr   = mls[r_], mur = muls[r_];
#pragma unroll 1
    for (int i = 0; i < 16; ++i) {
      int c = c0 + i;
      int kmax = min(r_, c);
      float mid = 0.f;
      for (int k = 0; k <= kmax; ++k) mid += Sls[r_ * 66 + k] * Sls[c * 66 + k];
      float val = mid + accS[i] + kap * mr * mls[c] - kn * mur * muls[c];
      Als[r_ * 66 + c] = left * val;
    }
  }
  __syncthreads();

  // in-place Gauss-Jordan sweep (SPD). thread: row rr, 16-col chunk cq
  int rr  = tid >> 2;
  int cq  = tid & 3;
  int cc0 = cq * 16;
  for (int p = 0; p < 64; ++p) {
    if (cq == (p >> 4)) fcol[rr] = Als[rr * 66 + p];
    if (rr == p) {
#pragma unroll
      for (int i = 0; i < 16; ++i) prow[cc0 + i] = Als[p * 66 + cc0 + i];
    }
    __syncthreads();
    float d  = 1.0f / fcol[p];
    float fr = fcol[rr];
#pragma unroll
    for (int i = 0; i < 16; ++i) {
      int c = cc0 + i;
      float q  = prow[c] * d;
      float ar = Als[rr * 66 + c];
      float res;
      if (rr == p) res = (c == p) ? d : q;
      else         res = (c == p) ? (-fr * d) : fmaf(-fr, q, ar);
      Als[rr * 66 + c] = res;
    }
    __syncthreads();
  }

  // A = 0.7*inv + 0.3*I, in place
#pragma unroll
  for (int i = 0; i < 16; ++i) {
    int c = cc0 + i;
    float a = 0.7f * Als[rr * 66 + c] + ((c == rr) ? 0.3f : 0.0f);
    Als[rr * 66 + c] = a;
  }
  __syncthreads();

  // Cholesky A = L L^T (lower, in place). 2 barriers/step.
  for (int k = 0; k < 64; ++k) {
    if (tid < 64) {
      float dv = Als[k * 66 + k];
      float rs = 1.0f / sqrtf(dv);
      float v  = (tid >= k) ? Als[tid * 66 + k] * rs : 0.f;
      Als[tid * 66 + k] = v;       // L[:,k] in place
      fcol[tid] = v;
    }
    __syncthreads();
    float lr = fcol[rr];
    if (rr > k) {
#pragma unroll
      for (int i = 0; i < 16; ++i) {
        int cc = cc0 + i;
        if (cc > k) Als[rr * 66 + cc] -= lr * fcol[cc];
      }
    }
    __syncthreads();
  }

  // write L^T bf16: LtG[j][e=rr][d] = (d>=e) ? L[d][e] : 0
  {
    unsigned short tmp[16];
#pragma unroll
    for (int i = 0; i < 16; ++i) {
      int d = cc0 + i;
      float v = (d >= rr) ? Als[d * 66 + rr] : 0.f;
      tmp[i] = f2bf(v);
    }
    uint4 w0, w1;
    w0.x = (unsigned)tmp[0]  | ((unsigned)tmp[1]  << 16);
    w0.y = (unsigned)tmp[2]  | ((unsigned)tmp[3]  << 16);
    w0.z = (unsigned)tmp[4]  | ((unsigned)tmp[5]  << 16);
    w0.w = (unsigned)tmp[6]  | ((unsigned)tmp[7]  << 16);
    w1.x = (unsigned)tmp[8]  | ((unsigned)tmp[9]  << 16);
    w1.y = (unsigned)tmp[10] | ((unsigned)tmp[11] << 16);
    w1.z = (unsigned)tmp[12] | ((unsigned)tmp[13] << 16);
    w1.w = (unsigned)tmp[14] | ((unsigned)tmp[15] << 16);
    *(uint4*)(LtG + j * 4096 + rr * 64 + cc0)     = w0;
    *(uint4*)(LtG + j * 4096 + rr * 64 + cc0 + 8) = w1;
  }

  // bias b[e] = (L^T mu)[e] = sum_{d>=e} L[d][e] * mu[d]
  if (tid < 64) {
    float s = 0.f;
    for (int d = tid; d < 64; ++d) s += Als[d * 66 + tid] * muls[d];
    Bg[j * 64 + tid] = s;
  }
}

// ---------------- Kernel 3: predict (MFMA, no LDS, no barriers) ----------------
// score[q,j] = -|| L_j^T y_q - L_j^T mu_j ||^2, accumulator init = -L^T mu.
// grid 512 = 128 query-tiles(256q) x 4 class-quarters; block 256 = 4 waves x 64 queries
__global__ __launch_bounds__(256) void predict_kernel(
    const unsigned short* __restrict__ Ybf, const unsigned short* __restrict__ Lt,
    const float* __restrict__ Bg, float* __restrict__ out) {
  int tid   = threadIdx.x;
  int lane  = tid & 63;
  int wave  = tid >> 6;
  int qt    = blockIdx.x >> 2;
  int cg    = blockIdx.x & 3;
  int cbase = cg * 16;
  int qbase = qt * 256 + wave * 64;
  int c = lane & 15, h = lane >> 4;

  // query fragments for this wave's 64 queries (B-operand, col = query)
  s16x8 bfr[4][2];
#pragma unroll
  for (int nt = 0; nt < 4; ++nt) {
    const unsigned short* yrow = Ybf + (size_t)(qbase + nt * 16 + c) * 64;
#pragma unroll
    for (int ks = 0; ks < 2; ++ks)
      bfr[nt][ks] = *(const s16x8*)(yrow + ks * 32 + h * 8);
  }

  // L^T fragment base for this lane; nonzero blocks (et,ks):
  // off(shorts) = et*1024 + ks*32  -> {0,1024, 32,1056,2080,3104}
  const unsigned short* ab = Lt + (size_t)cbase * 4096 + c * 64 + h * 8;
  s16x8 af0 = *(const s16x8*)(ab + 0);
  s16x8 af1 = *(const s16x8*)(ab + 1024);
  s16x8 af2 = *(const s16x8*)(ab + 32);
  s16x8 af3 = *(const s16x8*)(ab + 1056);
  s16x8 af4 = *(const s16x8*)(ab + 2080);
  s16x8 af5 = *(const s16x8*)(ab + 3104);

  float sc[16];
#pragma unroll
  for (int jj = 0; jj < 16; ++jj) {
    // prefetch next class's fragments (L2-resident)
    s16x8 an0, an1, an2, an3, an4, an5;
    if (jj < 15) {
      const unsigned short* an = ab + (size_t)(jj + 1) * 4096;
      an0 = *(const s16x8*)(an + 0);
      an1 = *(const s16x8*)(an + 1024);
      an2 = *(const s16x8*)(an + 32);
      an3 = *(const s16x8*)(an + 1056);
      an4 = *(const s16x8*)(an + 2080);
      an5 = *(const s16x8*)(an + 3104);
    }
    const float* bb = Bg + (size_t)(cbase + jj) * 64 + h * 4;
    float4 b0 = *(const float4*)(bb);
    float4 b1 = *(const float4*)(bb + 16);
    float4 b2 = *(const float4*)(bb + 32);
    float4 b3 = *(const float4*)(bb + 48);

    float ssel = 0.f;
#pragma unroll
    for (int nt = 0; nt < 4; ++nt) {
      f32x4 a0 = {-b0.x, -b0.y, -b0.z, -b0.w};
      f32x4 a1 = {-b1.x, -b1.y, -b1.z, -b1.w};
      f32x4 a2 = {-b2.x, -b2.y, -b2.z, -b2.w};
      f32x4 a3 = {-b3.x, -b3.y, -b3.z, -b3.w};
      a0 = __builtin_amdgcn_mfma_f32_16x16x32_bf16(
          __builtin_bit_cast(bf16x8, af0), __builtin_bit_cast(bf16x8, bfr[nt][0]), a0, 0, 0, 0);
      a1 = __builtin_amdgcn_mfma_f32_16x16x32_bf16(
          __builtin_bit_cast(bf16x8, af1), __builtin_bit_cast(bf16x8, bfr[nt][0]), a1, 0, 0, 0);
      a0 = __builtin_amdgcn_mfma_f32_16x16x32_bf16(
          __builtin_bit_cast(bf16x8, af2), __builtin_bit_cast(bf16x8, bfr[nt][1]), a0, 0, 0, 0);
      a1 = __builtin_amdgcn_mfma_f32_16x16x32_bf16(
          __builtin_bit_cast(bf16x8, af3), __builtin_bit_cast(bf16x8, bfr[nt][1]), a1, 0, 0, 0);
      a2 = __builtin_amdgcn_mfma_f32_16x16x32_bf16(
          __builtin_bit_cast(bf16x8, af4), __builtin_bit_cast(bf16x8, bfr[nt][1]), a2, 0, 0, 0);
      a3 = __builtin_amdgcn_mfma_f32_16x16x32_bf16(
          __builtin_bit_cast(bf16x8, af5), __builtin_bit_cast(bf16x8, bfr[nt][1]), a3, 0, 0, 0);
      float s = a0[0] * a0[0] + a0[1] * a0[1] + a0[2] * a0[2] + a0[3] * a0[3];
      s += a1[0] * a1[0] + a1[1] * a1[1] + a1[2] * a1[2] + a1[3] * a1[3];
      s += a2[0] * a2[0] + a2[1] * a2[1] + a2[2] * a2[2] + a2[3] * a2[3];
      s += a3[0] * a3[0] + a3[1] * a3[1] + a3[2] * a3[2] + a3[3] * a3[3];
      s += __shfl_xor(s, 16);
      s += __shfl_xor(s, 32);
      if (nt == h) ssel = s;   // lane keeps score for query h*16+c (== lane)
    }
    sc[jj] = -ssel;
    if (jj < 15) { af0 = an0; af1 = an1; af2 = an2; af3 = an3; af4 = an4; af5 = an5; }
  }

  float* orow = out + (size_t)(qbase + lane) * 64 + cbase;
#pragma unroll
  for (int k = 0; k < 4; ++k) {
    f32x4 v = { sc[4 * k], sc[4 * k + 1], sc[4 * k + 2], sc[4 * k + 3] };
    *(f32x4*)(orow + 4 * k) = v;
  }
}

extern "C" void kernel_launch(void* const* d_in, const int* in_sizes, int n_in,
                              void* d_out, int out_size, void* d_ws, size_t ws_size,
                              hipStream_t stream) {
  const float* Xs   = (const float*)d_in[0];
  const int*   ys   = (const int*)d_in[1];
  const float* Xq   = (const float*)d_in[2];
  const float* mg   = (const float*)d_in[3];
  const float* Sg   = (const float*)d_in[4];
  const float* nug  = (const float*)d_in[5];
  const float* kapg = (const float*)d_in[6];
  float* out = (float*)d_out;

  unsigned short* Ybf = (unsigned short*)d_ws;              // NQ*64 bf16 = 4 MB
  unsigned short* LtG = Ybf + (size_t)NQRY * 64;            // 64*4096 bf16 = 512 KB
  float* Bg = (float*)(LtG + (size_t)NCLS * 4096);          // 64*64 f32

  prep_queries<<<dim3(NQRY / 16), dim3(256), 0, stream>>>(Xq, Ybf);
  fit_classes<<<dim3(NCLS), dim3(256), 0, stream>>>(Xs, ys, mg, Sg, nug, kapg,
                                                    LtG, Bg);
  predict_kernel<<<dim3(512), dim3(256), 0, stream>>>(Ybf, LtG, Bg, out);
}

// Round 3
// 306.409 us; speedup vs baseline: 1.3341x; 1.3341x over previous
//
#include <hip/hip_runtime.h>
#include <stdint.h>

#define NSUP 1024
#define NQRY 32768
#define DIM  64
#define NCLS 64

typedef float  f32x4  __attribute__((ext_vector_type(4)));
typedef short  s16x8  __attribute__((ext_vector_type(8)));
typedef __bf16 bf16x8 __attribute__((ext_vector_type(8)));

static __device__ __forceinline__ unsigned short f2bf(float f) {
  unsigned u = __float_as_uint(f);
  u += 0x7FFFu + ((u >> 16) & 1u);           // round-to-nearest-even
  return (unsigned short)(u >> 16);
}

// ---------------- Kernel 1: normalize queries -> bf16, + Mid2 block ----------
// blocks [0,2048): prep 16 query rows each. block 2048: Mid2 = tril(S)tril(S)^T + kap*m m^T
__global__ __launch_bounds__(256) void prep_and_mid(
    const float* __restrict__ Xq, const float* __restrict__ mg,
    const float* __restrict__ Sg, const float* __restrict__ kapg,
    unsigned short* __restrict__ Ybf, float* __restrict__ Mid2) {
  __shared__ float Sls[64 * 65];
  __shared__ float mls[64];
  int tid = threadIdx.x;

  if (blockIdx.x < 2048) {
    int lane = tid & 63;
    int wave = tid >> 6;
    int row  = blockIdx.x * 16 + wave * 4 + (lane >> 4);
    int cb   = (lane & 15) * 4;
    float4 v = *(const float4*)(Xq + (size_t)row * 64 + cb);
    float ss = v.x * v.x + v.y * v.y + v.z * v.z + v.w * v.w;
    ss += __shfl_xor(ss, 1);
    ss += __shfl_xor(ss, 2);
    ss += __shfl_xor(ss, 4);
    ss += __shfl_xor(ss, 8);
    float inv = 1.0f / fmaxf(sqrtf(ss), 1e-12f);
    unsigned short a = f2bf(v.x * inv), b = f2bf(v.y * inv);
    unsigned short c = f2bf(v.z * inv), d = f2bf(v.w * inv);
    uint2 o;
    o.x = (unsigned)a | ((unsigned)b << 16);
    o.y = (unsigned)c | ((unsigned)d << 16);
    *(uint2*)(Ybf + (size_t)row * 64 + cb) = o;
    return;
  }

  // Mid2 block
  for (int i = tid; i < 4096; i += 256) Sls[(i >> 6) * 65 + (i & 63)] = Sg[i];
  if (tid < 64) mls[tid] = mg[tid];
  __syncthreads();
  float kap = kapg[0];
  int r_ = tid & 63, cblk = tid >> 6, c0 = cblk * 16;
#pragma unroll 1
  for (int i = 0; i < 16; ++i) {
    int cc = c0 + i;
    int kmax = min(r_, cc);
    float mid = 0.f;
    for (int k = 0; k <= kmax; ++k) mid += Sls[r_ * 65 + k] * Sls[cc * 65 + k];
    Mid2[r_ * 64 + cc] = mid + kap * mls[r_] * mls[cc];
  }
}

// ---------------- Kernel 2: fit (one block per class, register-resident rows)
// thread (rr=tid>>2, cq=tid&3) owns row rr, cols [cq*16, cq*16+16) in regs.
// GJ inverse + Cholesky: 1 barrier/pivot, double-buffered pivot col/row in LDS.
__global__ __launch_bounds__(256) void fit_classes(
    const float* __restrict__ Xs, const int* __restrict__ ys,
    const float* __restrict__ mg, const float* __restrict__ Mid2,
    const float* __restrict__ nug, const float* __restrict__ kapg,
    unsigned short* __restrict__ LtG, float* __restrict__ Bg) {
  __shared__ float xsch[16][68];
  __shared__ float muls[64];
  __shared__ float fcol[2][64];
  __shared__ float prow[2][64];
  __shared__ float Lls[64 * 65];
  __shared__ int   lst[64];
  __shared__ int   cnts[2];

  int tid = threadIdx.x;
  int j   = blockIdx.x;
  int rr = tid >> 2, cq = tid & 3, cc0 = cq * 16;

  // wave 0: match list + counts (Nj, and reference's N0 = count of class 0)
  if (tid < 64) {
    int lane = tid;
    int cnt = 0, n0 = 0;
    for (int b = 0; b < NSUP; b += 64) {
      int yv = ys[b + lane];
      unsigned long long mj = __ballot(yv == j);
      unsigned long long m0 = __ballot(yv == 0);
      if (lane == 0) {
        n0 += (int)__popcll(m0);
        while (mj && cnt < 64) { int bit = __builtin_ctzll(mj); lst[cnt++] = b + bit; mj &= mj - 1; }
      }
    }
    if (lane == 0) { cnts[0] = cnt; cnts[1] = n0; }
  }
  __syncthreads();
  int cnt = cnts[0], n0 = cnts[1];

  // acc init = Mid2 row chunk (middle + kappa*m m^T), coalesced
  float acc[16];
  {
    const float* mrow = Mid2 + rr * 64 + cc0;
    float4 m0 = *(const float4*)(mrow + 0);
    float4 m1 = *(const float4*)(mrow + 4);
    float4 m2 = *(const float4*)(mrow + 8);
    float4 m3 = *(const float4*)(mrow + 12);
    acc[0]=m0.x; acc[1]=m0.y; acc[2]=m0.z; acc[3]=m0.w;
    acc[4]=m1.x; acc[5]=m1.y; acc[6]=m1.z; acc[7]=m1.w;
    acc[8]=m2.x; acc[9]=m2.y; acc[10]=m2.z; acc[11]=m2.w;
    acc[12]=m3.x; acc[13]=m3.y; acc[14]=m3.z; acc[15]=m3.w;
  }

  // Ssum over matched samples (normalized rows staged via LDS)
  float sumx = 0.f;
  for (int s0 = 0; s0 < cnt; s0 += 16) {
    int nch = min(16, cnt - s0);
    int s = tid >> 4, f = tid & 15;
    if (s < nch) {
      int n = lst[s0 + s];
      float4 v = *(const float4*)(Xs + (size_t)n * 64 + f * 4);
      float ss = v.x * v.x + v.y * v.y + v.z * v.z + v.w * v.w;
      ss += __shfl_xor(ss, 1); ss += __shfl_xor(ss, 2);
      ss += __shfl_xor(ss, 4); ss += __shfl_xor(ss, 8);
      float inv = 1.0f / fmaxf(sqrtf(ss), 1e-12f);
      xsch[s][f * 4 + 0] = v.x * inv;
      xsch[s][f * 4 + 1] = v.y * inv;
      xsch[s][f * 4 + 2] = v.z * inv;
      xsch[s][f * 4 + 3] = v.w * inv;
    }
    __syncthreads();
    for (int s2 = 0; s2 < nch; ++s2) {
      float ar = xsch[s2][rr];
      sumx += ar;
#pragma unroll
      for (int i = 0; i < 16; ++i) acc[i] += ar * xsch[s2][cc0 + i];
    }
    __syncthreads();
  }

  // mu
  float kap = kapg[0], nuv = nug[0];
  float Njf = (float)cnt, N0f = (float)n0;
  float mean_r = sumx / Njf;
  float head_r = kap / (kap + N0f) * mg[rr] + N0f / (kap + N0f);
  float mu_r = head_r * mean_r;
  if (cq == 0) muls[rr] = mu_r;
  __syncthreads();

  // sigma row chunk in regs
  float a[16];
  {
    float left = 1.0f / (nuv + Njf + (float)DIM + 2.0f);
    float kn = kap + Njf;
#pragma unroll
    for (int i = 0; i < 16; ++i)
      a[i] = left * (acc[i] - kn * mu_r * muls[cc0 + i]);
  }

  // GJ init: pivot-0 column/row into buffer 0
  {
    float fsel = 0.f;
#pragma unroll
    for (int i = 0; i < 16; ++i) fsel = (cc0 + i == 0) ? a[i] : fsel;
    if (cq == 0) fcol[0][rr] = fsel;
    if (rr == 0) {
#pragma unroll
      for (int i = 0; i < 16; ++i) prow[0][cc0 + i] = a[i];
    }
  }
  __syncthreads();

  // GJ sweep: 1 barrier per pivot
  for (int p = 0; p < 64; ++p) {
    int pb = p & 1;
    float d  = 1.0f / fcol[pb][p];
    float fr = fcol[pb][rr];
#pragma unroll
    for (int i = 0; i < 16; ++i) {
      int c = cc0 + i;
      float q  = prow[pb][c] * d;
      float ar = a[i];
      float res;
      if (rr == p) res = (c == p) ? d : q;
      else         res = (c == p) ? (-fr * d) : fmaf(-fr, q, ar);
      a[i] = res;
    }
    if (p < 63) {
      float fsel = 0.f;
#pragma unroll
      for (int i = 0; i < 16; ++i) fsel = (cc0 + i == p + 1) ? a[i] : fsel;
      if (cq == ((p + 1) >> 4)) fcol[pb ^ 1][rr] = fsel;
      if (rr == p + 1) {
#pragma unroll
        for (int i = 0; i < 16; ++i) prow[pb ^ 1][cc0 + i] = a[i];
      }
    }
    __syncthreads();
  }

  // A = 0.7*inv + 0.3*I (regs), then Cholesky A = L L^T, 1 barrier per column
#pragma unroll
  for (int i = 0; i < 16; ++i)
    a[i] = 0.7f * a[i] + ((cc0 + i == rr) ? 0.3f : 0.f);
  {
    float fsel = 0.f;
#pragma unroll
    for (int i = 0; i < 16; ++i) fsel = (cc0 + i == 0) ? a[i] : fsel;
    if (cq == 0) fcol[0][rr] = fsel;
  }
  __syncthreads();

  for (int k = 0; k < 64; ++k) {
    int pb = k & 1;
    float akk = fcol[pb][k];
    float rs  = 1.0f / sqrtf(akk);
    float vr  = fcol[pb][rr] * rs;
#pragma unroll
    for (int i = 0; i < 16; ++i) {
      int c = cc0 + i;
      if (c == k)              a[i] = (rr >= k) ? vr : 0.f;
      else if (rr > k && c > k) a[i] -= vr * (fcol[pb][c] * rs);
    }
    if (k < 63) {
      float fsel = 0.f;
#pragma unroll
      for (int i = 0; i < 16; ++i) fsel = (cc0 + i == k + 1) ? a[i] : fsel;
      if (cq == ((k + 1) >> 4)) fcol[pb ^ 1][rr] = fsel;
    }
    __syncthreads();
  }

  // L (lower) -> LDS; emit L^T bf16 and bias b = L^T mu
#pragma unroll
  for (int i = 0; i < 16; ++i) {
    int c = cc0 + i;
    Lls[rr * 65 + c] = (c <= rr) ? a[i] : 0.f;
  }
  __syncthreads();
  {
    unsigned short tmp[16];
#pragma unroll
    for (int i = 0; i < 16; ++i) tmp[i] = f2bf(Lls[(cc0 + i) * 65 + rr]);
    uint4 w0, w1;
    w0.x = (unsigned)tmp[0]  | ((unsigned)tmp[1]  << 16);
    w0.y = (unsigned)tmp[2]  | ((unsigned)tmp[3]  << 16);
    w0.z = (unsigned)tmp[4]  | ((unsigned)tmp[5]  << 16);
    w0.w = (unsigned)tmp[6]  | ((unsigned)tmp[7]  << 16);
    w1.x = (unsigned)tmp[8]  | ((unsigned)tmp[9]  << 16);
    w1.y = (unsigned)tmp[10] | ((unsigned)tmp[11] << 16);
    w1.z = (unsigned)tmp[12] | ((unsigned)tmp[13] << 16);
    w1.w = (unsigned)tmp[14] | ((unsigned)tmp[15] << 16);
    *(uint4*)(LtG + j * 4096 + rr * 64 + cc0)     = w0;
    *(uint4*)(LtG + j * 4096 + rr * 64 + cc0 + 8) = w1;
  }
  {
    float s = 0.f;
#pragma unroll
    for (int i = 0; i < 16; ++i) s += Lls[(cc0 + i) * 65 + rr] * muls[cc0 + i];
    s += __shfl_xor(s, 1);
    s += __shfl_xor(s, 2);
    if (cq == 0) Bg[j * 64 + rr] = s;
  }
}

// ---------------- Kernel 3: predict (MFMA, no LDS/barriers, hoist-capped) ----
// score[q,j] = -|| L_j^T y_q - L_j^T mu_j ||^2; acc init = -L^T mu.
// grid 512 = 128 qtiles(256q) x 4 class-quarters; block 256 = 4 waves x 64 q.
__global__ __launch_bounds__(256) void predict_kernel(
    const unsigned short* __restrict__ Ybf, const unsigned short* __restrict__ Lt,
    const float* __restrict__ Bg, float* __restrict__ out) {
  int tid   = threadIdx.x;
  int lane  = tid & 63;
  int wave  = tid >> 6;
  int qt    = blockIdx.x >> 2;
  int cg    = blockIdx.x & 3;
  int cbase = cg * 16;
  int qbase = qt * 256 + wave * 64;
  int c = lane & 15, h = lane >> 4;

  // query fragments (B-operand, col = query)
  s16x8 bfr[4][2];
#pragma unroll
  for (int nt = 0; nt < 4; ++nt) {
    const unsigned short* yrow = Ybf + (size_t)(qbase + nt * 16 + c) * 64;
#pragma unroll
    for (int ks = 0; ks < 2; ++ks)
      bfr[nt][ks] = *(const s16x8*)(yrow + ks * 32 + h * 8);
  }

  const unsigned short* ab    = Lt + (size_t)cbase * 4096 + c * 64 + h * 8;
  const float*          bbase = Bg + (size_t)cbase * 64 + h * 4;
  float*                orow  = out + (size_t)(qbase + lane) * 64 + cbase;

#pragma unroll 1
  for (int g = 0; g < 4; ++g) {
    float sc4[4];
#pragma unroll
    for (int u = 0; u < 4; ++u) {
      int jj = g * 4 + u;
      // L^T fragments: nonzero (et,ks) blocks of upper-tri, offsets in shorts
      const unsigned short* aj = ab + (size_t)jj * 4096;
      s16x8 af0 = *(const s16x8*)(aj + 0);
      s16x8 af1 = *(const s16x8*)(aj + 1024);
      s16x8 af2 = *(const s16x8*)(aj + 32);
      s16x8 af3 = *(const s16x8*)(aj + 1056);
      s16x8 af4 = *(const s16x8*)(aj + 2080);
      s16x8 af5 = *(const s16x8*)(aj + 3104);
      const float* bb = bbase + (size_t)jj * 64;
      float4 b0 = *(const float4*)(bb);
      float4 b1 = *(const float4*)(bb + 16);
      float4 b2 = *(const float4*)(bb + 32);
      float4 b3 = *(const float4*)(bb + 48);

      float ssel = 0.f;
#pragma unroll
      for (int nt = 0; nt < 4; ++nt) {
        f32x4 a0 = {-b0.x, -b0.y, -b0.z, -b0.w};
        f32x4 a1 = {-b1.x, -b1.y, -b1.z, -b1.w};
        f32x4 a2 = {-b2.x, -b2.y, -b2.z, -b2.w};
        f32x4 a3 = {-b3.x, -b3.y, -b3.z, -b3.w};
        a0 = __builtin_amdgcn_mfma_f32_16x16x32_bf16(
            __builtin_bit_cast(bf16x8, af0), __builtin_bit_cast(bf16x8, bfr[nt][0]), a0, 0, 0, 0);
        a1 = __builtin_amdgcn_mfma_f32_16x16x32_bf16(
            __builtin_bit_cast(bf16x8, af1), __builtin_bit_cast(bf16x8, bfr[nt][0]), a1, 0, 0, 0);
        a0 = __builtin_amdgcn_mfma_f32_16x16x32_bf16(
            __builtin_bit_cast(bf16x8, af2), __builtin_bit_cast(bf16x8, bfr[nt][1]), a0, 0, 0, 0);
        a1 = __builtin_amdgcn_mfma_f32_16x16x32_bf16(
            __builtin_bit_cast(bf16x8, af3), __builtin_bit_cast(bf16x8, bfr[nt][1]), a1, 0, 0, 0);
        a2 = __builtin_amdgcn_mfma_f32_16x16x32_bf16(
            __builtin_bit_cast(bf16x8, af4), __builtin_bit_cast(bf16x8, bfr[nt][1]), a2, 0, 0, 0);
        a3 = __builtin_amdgcn_mfma_f32_16x16x32_bf16(
            __builtin_bit_cast(bf16x8, af5), __builtin_bit_cast(bf16x8, bfr[nt][1]), a3, 0, 0, 0);
        float s = a0[0] * a0[0] + a0[1] * a0[1] + a0[2] * a0[2] + a0[3] * a0[3];
        s += a1[0] * a1[0] + a1[1] * a1[1] + a1[2] * a1[2] + a1[3] * a1[3];
        s += a2[0] * a2[0] + a2[1] * a2[1] + a2[2] * a2[2] + a2[3] * a2[3];
        s += a3[0] * a3[0] + a3[1] * a3[1] + a3[2] * a3[2] + a3[3] * a3[3];
        s += __shfl_xor(s, 16);
        s += __shfl_xor(s, 32);
        if (nt == h) ssel = s;   // lane keeps score for query h*16+c (== lane)
      }
      sc4[u] = -ssel;
    }
    f32x4 v = { sc4[0], sc4[1], sc4[2], sc4[3] };
    *(f32x4*)(orow + g * 4) = v;   // 4 groups fill one 64B sector -> L2 merges
  }
}

extern "C" void kernel_launch(void* const* d_in, const int* in_sizes, int n_in,
                              void* d_out, int out_size, void* d_ws, size_t ws_size,
                              hipStream_t stream) {
  const float* Xs   = (const float*)d_in[0];
  const int*   ys   = (const int*)d_in[1];
  const float* Xq   = (const float*)d_in[2];
  const float* mg   = (const float*)d_in[3];
  const float* Sg   = (const float*)d_in[4];
  const float* nug  = (const float*)d_in[5];
  const float* kapg = (const float*)d_in[6];
  float* out = (float*)d_out;

  unsigned short* Ybf = (unsigned short*)d_ws;              // NQ*64 bf16 = 4 MB
  unsigned short* LtG = Ybf + (size_t)NQRY * 64;            // 64*4096 bf16 = 512 KB
  float* Bg   = (float*)(LtG + (size_t)NCLS * 4096);        // 64*64 f32
  float* Mid2 = Bg + NCLS * 64;                             // 64*64 f32

  prep_and_mid<<<dim3(2049), dim3(256), 0, stream>>>(Xq, mg, Sg, kapg, Ybf, Mid2);
  fit_classes<<<dim3(NCLS), dim3(256), 0, stream>>>(Xs, ys, mg, Mid2, nug, kapg,
                                                    LtG, Bg);
  predict_kernel<<<dim3(512), dim3(256), 0, stream>>>(Ybf, LtG, Bg, out);
}